// Round 9
// baseline (174.676 us; speedup 1.0000x reference)
//
#include <hip/hip_runtime.h>
#include <stdint.h>

#define TB 256

typedef __bf16 bf16x8 __attribute__((ext_vector_type(8)));
typedef float f32x4 __attribute__((ext_vector_type(4)));

__device__ __forceinline__ unsigned short f2bf(float f) {
  uint32_t u = __builtin_bit_cast(uint32_t, f);
  u += 0x7fffu + ((u >> 16) & 1u);
  return (unsigned short)(u >> 16);
}
__device__ __forceinline__ uint32_t pk2(float a, float b) {
  return (uint32_t)f2bf(a) | ((uint32_t)f2bf(b) << 16);
}

#define LD8(p) (*reinterpret_cast<const bf16x8*>(p))

// Fragment layouts (shorts):  frag(U, kstep, ks, lane) at U*32768 + kstep*1024 + ks*512 + lane*8
//   xf: U = R (row16-tile, 0..255);  wf: U = C (col16-tile): 0..74 = lvl2 groups (3/group),
//   75..77 = root W (cols 0..31 real, rest 0).  lane=(lq*16+lr) holds col/row=base+lr,
//   k = kstep*64 + ks*32 + lq*8 .. +8  — identical mapping to the LDS-read path of prior rounds.

// ---------------- kernel: fused prep (frag-order transposes) ----------------
// [0,2048): x -> xf       (64 rows x 64 k per block)
// [2048,2848): W_lvl2 -> wf C=n*3+cq   (per block: one n, one kstep)
// [2848,2880): W_root -> wf C=75..77   (per block: one kstep)
// 2880: labels normalize + pengl=0
__global__ __launch_bounds__(TB) void k_prep(const float* __restrict__ x,
                                             const float* __restrict__ wl,
                                             const float* __restrict__ wr,
                                             const int* __restrict__ labraw,
                                             unsigned short* __restrict__ xf,
                                             unsigned short* __restrict__ wf,
                                             int* __restrict__ lab32,
                                             float* __restrict__ pengl) {
  __shared__ float ld[64 * 67];
  int bid = blockIdx.x, t = threadIdx.x;
  if (bid < 2048) {
    int rb = bid >> 5, kstep = bid & 31;
    int r0 = rb * 64, k0 = kstep * 64;
#pragma unroll
    for (int u = 0; u < 4; u++) {
      int ft = u * 256 + t;            // 1024 float4 tiles
      int i = ft >> 4, j4 = ft & 15;
      float4 v = *reinterpret_cast<const float4*>(x + (size_t)(r0 + i) * 2048 + k0 + j4 * 4);
      ld[i * 67 + j4 * 4 + 0] = v.x; ld[i * 67 + j4 * 4 + 1] = v.y;
      ld[i * 67 + j4 * 4 + 2] = v.z; ld[i * 67 + j4 * 4 + 3] = v.w;
    }
    __syncthreads();
#pragma unroll
    for (int u = 0; u < 2; u++) {
      int c = u * 256 + t;             // 512 output chunks
      int subR = c >> 7, ks = (c >> 6) & 1, lane = c & 63;
      int row = subR * 16 + (lane & 15);
      int kl = ks * 32 + (lane >> 4) * 8;
      const float* s = &ld[row * 67 + kl];
      uint4 o = make_uint4(pk2(s[0], s[1]), pk2(s[2], s[3]), pk2(s[4], s[5]), pk2(s[6], s[7]));
      size_t R = rb * 4 + subR;
      *reinterpret_cast<uint4*>(xf + ((R * 32 + kstep) * 2 + ks) * 512 + lane * 8) = o;
    }
  } else if (bid < 2848) {
    int b2 = bid - 2048;
    int n = b2 >> 5, kstep = b2 & 31;
    const float* src = wl + ((size_t)n * 2048 + kstep * 64) * 41;
    for (int u = 0; u < 11; u++) { int lin = t + TB * u; if (lin < 2624) ld[lin] = src[lin]; }
    __syncthreads();
#pragma unroll
    for (int u = 0; u < 2; u++) {
      int c = u * 256 + t;
      if (c < 384) {
        int cq = c >> 7, ks = (c >> 6) & 1, lane = c & 63;
        int col = cq * 16 + (lane & 15);
        int kl = ks * 32 + (lane >> 4) * 8;
        float v[8];
#pragma unroll
        for (int j = 0; j < 8; j++) v[j] = (col < 41) ? ld[(kl + j) * 41 + col] : 0.f;
        uint4 o = make_uint4(pk2(v[0], v[1]), pk2(v[2], v[3]), pk2(v[4], v[5]), pk2(v[6], v[7]));
        size_t C = n * 3 + cq;
        *reinterpret_cast<uint4*>(wf + ((C * 32 + kstep) * 2 + ks) * 512 + lane * 8) = o;
      }
    }
  } else if (bid < 2880) {
    int kstep = bid - 2848;
    const float* src = wr + (size_t)kstep * 64 * 26;
    for (int u = 0; u < 7; u++) { int lin = t + TB * u; if (lin < 1664) ld[lin] = src[lin]; }
    __syncthreads();
#pragma unroll
    for (int u = 0; u < 2; u++) {
      int c = u * 256 + t;
      if (c < 384) {
        int cq = c >> 7, ks = (c >> 6) & 1, lane = c & 63;
        int col = cq * 16 + (lane & 15);
        int kl = ks * 32 + (lane >> 4) * 8;
        float v[8];
#pragma unroll
        for (int j = 0; j < 8; j++) v[j] = (col < 26) ? ld[(kl + j) * 26 + col] : 0.f;
        uint4 o = make_uint4(pk2(v[0], v[1]), pk2(v[2], v[3]), pk2(v[4], v[5]), pk2(v[6], v[7]));
        size_t C = 75 + cq;
        *reinterpret_cast<uint4*>(wf + ((C * 32 + kstep) * 2 + ks) * 512 + lane * 8) = o;
      }
    }
  } else {
    __shared__ int orred;
    if (t == 0) { orred = 0; pengl[0] = 0.f; }
    __syncthreads();
    int acc = 0;
    for (int i = t; i < 2048; i += TB) acc |= labraw[2 * i + 1];
    atomicOr(&orred, acc);
    __syncthreads();
    bool i64 = (orred == 0);
    for (int i = t; i < 4096; i += TB) lab32[i] = i64 ? labraw[2 * i] : labraw[i];
  }
}

// ---------------- kernel: root GEMM + softmax + ce_root (frag streaming) ----------------
// 256 blocks x 256 thr; 16 rows/block; 4 waves split K 4-way (8 ksteps each); LDS reduce
__global__ __launch_bounds__(TB) void k_root(const unsigned short* __restrict__ xf,
                                             const unsigned short* __restrict__ wf,
                                             const float* __restrict__ br,
                                             const int* __restrict__ labels,
                                             float* __restrict__ rootp,
                                             float* __restrict__ pengl) {
  __shared__ float red[4 * 64 * 8];
  int bid = blockIdx.x;
  int tid = threadIdx.x, lane = tid & 63, wave = tid >> 6;
  int lq = lane >> 4, lr = lane & 15;
  f32x4 acc[2] = {};
  const unsigned short* xb = xf + (size_t)bid * 32768 + lane * 8;
  const unsigned short* w0 = wf + (size_t)75 * 32768 + lane * 8;
  const unsigned short* w1 = wf + (size_t)76 * 32768 + lane * 8;
  int kb0 = wave * 8 * 1024;  // this wave's kstep base (shorts)

#define RLOAD(W, X, kb)                                                  \
  do { _Pragma("unroll") for (int ks = 0; ks < 2; ks++) {                \
      W[ks][0] = LD8(w0 + (kb) + ks * 512);                              \
      W[ks][1] = LD8(w1 + (kb) + ks * 512);                              \
      X[ks] = LD8(xb + (kb) + ks * 512); } } while (0)
#define RMFMA(W, X)                                                      \
  do { _Pragma("unroll") for (int ks = 0; ks < 2; ks++)                  \
      _Pragma("unroll") for (int mt = 0; mt < 2; mt++)                   \
        acc[mt] = __builtin_amdgcn_mfma_f32_16x16x32_bf16(W[ks][mt], X[ks], acc[mt], 0, 0, 0); } while (0)

  bf16x8 A[2][2], Xa[2], B[2][2], Xb[2];
  RLOAD(A, Xa, kb0);
#pragma unroll
  for (int tt = 0; tt < 3; ++tt) {
    RLOAD(B, Xb, kb0 + (2 * tt + 1) * 1024); RMFMA(A, Xa);
    RLOAD(A, Xa, kb0 + (2 * tt + 2) * 1024); RMFMA(B, Xb);
  }
  RLOAD(B, Xb, kb0 + 7 * 1024); RMFMA(A, Xa); RMFMA(B, Xb);

  int li = (wave * 64 + lane) * 8;
#pragma unroll
  for (int mt = 0; mt < 2; mt++)
#pragma unroll
    for (int r = 0; r < 4; r++) red[li + mt * 4 + r] = acc[mt][r];
  __syncthreads();
  if (wave == 0) {
    float lg[2][4];
    float m = -1e30f;
#pragma unroll
    for (int mt = 0; mt < 2; mt++)
#pragma unroll
      for (int r = 0; r < 4; r++) {
        float v = 0.f;
#pragma unroll
        for (int w = 0; w < 4; w++) v += red[(w * 64 + lane) * 8 + mt * 4 + r];
        int wc = mt * 16 + lq * 4 + r;
        v += (wc < 26) ? br[wc] : -1e30f;
        lg[mt][r] = v;
        m = fmaxf(m, v);
      }
    m = fmaxf(m, __shfl_xor(m, 16));
    m = fmaxf(m, __shfl_xor(m, 32));
    float s = 0.f;
#pragma unroll
    for (int mt = 0; mt < 2; mt++)
#pragma unroll
      for (int r = 0; r < 4; r++) s += expf(lg[mt][r] - m);
    s += __shfl_xor(s, 16);
    s += __shfl_xor(s, 32);
    float ls = logf(s);
    int b = bid * 16 + lr;
    int lab = labels[b];
    int j = lab / 40;
    float pen = 0.f;
#pragma unroll
    for (int mt = 0; mt < 2; mt++)
#pragma unroll
      for (int r = 0; r < 4; r++) {
        int wc = mt * 16 + lq * 4 + r;
        float lp = lg[mt][r] - m - ls;
        if (wc < 26) rootp[(size_t)b * 32 + wc] = expf(lp);
        if (wc == j + 1) pen -= lp;
      }
    for (int off = 32; off; off >>= 1) pen += __shfl_down(pen, off);
    if (lane == 0) atomicAdd(pengl, pen * (1.f / 4096.f));
  }
}

// ---------------- kernel: lvl2 grouped GEMM, pure frag streaming ----------------
// 832 blocks x 64 thr (1 wave); wave = 64 rows x 96 cols (2 groups); no LDS, no barriers;
// all blocks co-resident (3.25 waves/CU); double-buffered frag regs, 1-step lookahead.
__global__ __launch_bounds__(64) void k_lvl2(const unsigned short* __restrict__ xf,
                                             const unsigned short* __restrict__ wf,
                                             const float* __restrict__ bl,
                                             const int* __restrict__ labels,
                                             const float* __restrict__ rootp,
                                             float* __restrict__ out,
                                             float* __restrict__ pengl) {
  int bid = blockIdx.x;                      // 832 = 13 wc * 64 rt
  int swz = (bid & 7) * 104 + (bid >> 3);    // XCD-chunked, bijective (832 = 8*104)
  int wcb = swz / 64, rt = swz % 64;         // wc-major chunks: each XCD's w slice L2-hot
  int lane = threadIdx.x;
  int lq = lane >> 4, lr = lane & 15;
  f32x4 acc[6][4] = {};
  const unsigned short* wb[6];
  const unsigned short* xb[4];
#pragma unroll
  for (int c = 0; c < 6; c++) wb[c] = wf + (size_t)(wcb * 6 + c) * 32768 + lane * 8;
#pragma unroll
  for (int nt = 0; nt < 4; nt++) xb[nt] = xf + (size_t)(rt * 4 + nt) * 32768 + lane * 8;

#define LLOAD(W, X, kb)                                                  \
  do { _Pragma("unroll") for (int ks = 0; ks < 2; ks++) {                \
      _Pragma("unroll") for (int c = 0; c < 6; c++)                      \
        W[ks][c] = LD8(wb[c] + (kb) + ks * 512);                         \
      _Pragma("unroll") for (int nt = 0; nt < 4; nt++)                   \
        X[ks][nt] = LD8(xb[nt] + (kb) + ks * 512); } } while (0)
#define LMFMA(W, X)                                                      \
  do { _Pragma("unroll") for (int ks = 0; ks < 2; ks++)                  \
      _Pragma("unroll") for (int mt = 0; mt < 6; mt++)                   \
        _Pragma("unroll") for (int nt = 0; nt < 4; nt++)                 \
          acc[mt][nt] = __builtin_amdgcn_mfma_f32_16x16x32_bf16(W[ks][mt], X[ks][nt], acc[mt][nt], 0, 0, 0); } while (0)

  bf16x8 A[2][6], Xa[2][4], B[2][6], Xb[2][4];
  LLOAD(A, Xa, 0);
#pragma unroll 1
  for (int tt = 0; tt < 15; ++tt) {
    LLOAD(B, Xb, (2 * tt + 1) * 1024);
    LMFMA(A, Xa);
    LLOAD(A, Xa, (2 * tt + 2) * 1024);
    LMFMA(B, Xb);
  }
  LLOAD(B, Xb, 31 * 1024);
  LMFMA(A, Xa);
  LMFMA(B, Xb);

  // epilogue: 2 groups per wave; softmax per row (row spread over 4 lq-lanes)
  int b0 = rt * 64;
  float pen = 0.f;
#pragma unroll
  for (int gi = 0; gi < 2; gi++) {
    int n = wcb * 2 + gi;
    bool valid = (n < 25);
    float bb[3][4];
#pragma unroll
    for (int q = 0; q < 3; q++)
#pragma unroll
      for (int r = 0; r < 4; r++) {
        int wcg = q * 16 + lq * 4 + r;
        bb[q][r] = (valid && wcg < 41) ? bl[n * 41 + wcg] : -1e30f;
      }
#pragma unroll
    for (int nt = 0; nt < 4; nt++) {
      int b = b0 + nt * 16 + lr;
      float lg[3][4];
      float m = -1e30f;
#pragma unroll
      for (int q = 0; q < 3; q++)
#pragma unroll
        for (int r = 0; r < 4; r++) {
          float v = acc[gi * 3 + q][nt][r] + bb[q][r];
          lg[q][r] = v;
          m = fmaxf(m, v);
        }
      m = fmaxf(m, __shfl_xor(m, 16));
      m = fmaxf(m, __shfl_xor(m, 32));
      float s = 0.f;
#pragma unroll
      for (int q = 0; q < 3; q++)
#pragma unroll
        for (int r = 0; r < 4; r++) s += expf(lg[q][r] - m);
      s += __shfl_xor(s, 16);
      s += __shfl_xor(s, 32);
      float ls = logf(s);
      float rp = valid ? rootp[(size_t)b * 32 + (n + 1)] : 0.f;
      int lab = labels[b];
      int j = lab / 40;
      int sub = (j == n) ? (lab - j * 40 + 1) : 0;
#pragma unroll
      for (int q = 0; q < 3; q++)
#pragma unroll
        for (int r = 0; r < 4; r++) {
          int wcg = q * 16 + lq * 4 + r;
          float lp = lg[q][r] - m - ls;
          if (valid && wcg >= 1 && wcg < 41) out[(size_t)b * 1000 + n * 40 + wcg - 1] = expf(lp) * rp;
          if (valid && wcg == sub) pen -= lp;
        }
    }
  }
  for (int off = 32; off; off >>= 1) pen += __shfl_down(pen, off);
  if (lane == 0) atomicAdd(pengl, pen * (1.f / 8192.f));
}

extern "C" void kernel_launch(void* const* d_in, const int* in_sizes, int n_in,
                              void* d_out, int out_size, void* d_ws, size_t ws_size,
                              hipStream_t stream) {
  const float* x = (const float*)d_in[0];
  const int* labels_raw = (const int*)d_in[1];
  const float* wroot = (const float*)d_in[2];
  const float* broot = (const float*)d_in[3];
  const float* wlvl2 = (const float*)d_in[4];
  const float* blvl2 = (const float*)d_in[5];
  float* out = (float*)d_out;
  float* pengl = out + 4096000;

  char* ws = (char*)d_ws;
  unsigned short* xf = (unsigned short*)ws;                     // 16,777,216 B (256 tiles)
  unsigned short* wf = (unsigned short*)(ws + 16777216);        //  5,111,808 B (78 tiles)
  float* rootp = (float*)(ws + 21889024);                       //    524,288 B
  int* lab32 = (int*)(ws + 22413312);                           //     16,384 B

  k_prep<<<2881, TB, 0, stream>>>(x, wlvl2, wroot, labels_raw, xf, wf, lab32, pengl);
  k_root<<<256, TB, 0, stream>>>(xf, wf, broot, lab32, rootp, pengl);
  k_lvl2<<<832, 64, 0, stream>>>(xf, wf, blvl2, lab32, rootp, out, pengl);
}

// Round 10
// 152.042 us; speedup vs baseline: 1.1489x; 1.1489x over previous
//
#include <hip/hip_runtime.h>
#include <stdint.h>

#define TB 256

typedef __bf16 bf16x8 __attribute__((ext_vector_type(8)));
typedef float f32x4 __attribute__((ext_vector_type(4)));

#define AS1 __attribute__((address_space(1)))
#define AS3 __attribute__((address_space(3)))
#define GLOAD16(gp, lp) __builtin_amdgcn_global_load_lds( \
    (const AS1 unsigned int*)(gp), (AS3 unsigned int*)(lp), 16, 0, 0)

__device__ __forceinline__ unsigned short f2bf(float f) {
  uint32_t u = __builtin_bit_cast(uint32_t, f);
  u += 0x7fffu + ((u >> 16) & 1u);
  return (unsigned short)(u >> 16);
}

// ---------------- kernel: fused prep ----------------
// [0,4096): x f32 -> xbf row-major [4096][2048]
// [4096,4896): W_lvl2 -> wlt[col][k], col = n*48+c in [0,1200)
// [4896,4928): W_root -> wlt cols 1200..1231 (26 real, 27..31 zero)
// 4928: zero wlt cols 1232..1279 ; 4929: labels + pengl=0
__global__ __launch_bounds__(TB) void k_prep(const float* __restrict__ x,
                                             const float* __restrict__ wl,
                                             const float* __restrict__ wr,
                                             const int* __restrict__ labraw,
                                             unsigned short* __restrict__ xbf,
                                             unsigned short* __restrict__ wlt,
                                             int* __restrict__ lab32,
                                             float* __restrict__ pengl) {
  int bid = blockIdx.x, t = threadIdx.x;
  if (bid < 4096) {
    int idx = bid * TB + t;
    const float4* xin = reinterpret_cast<const float4*>(x);
    float4 a = xin[idx * 2], b = xin[idx * 2 + 1];
    uint32_t p0 = (uint32_t)f2bf(a.x) | ((uint32_t)f2bf(a.y) << 16);
    uint32_t p1 = (uint32_t)f2bf(a.z) | ((uint32_t)f2bf(a.w) << 16);
    uint32_t p2 = (uint32_t)f2bf(b.x) | ((uint32_t)f2bf(b.y) << 16);
    uint32_t p3 = (uint32_t)f2bf(b.z) | ((uint32_t)f2bf(b.w) << 16);
    reinterpret_cast<uint4*>(xbf)[idx] = make_uint4(p0, p1, p2, p3);
  } else if (bid < 4928) {
    __shared__ float ld_f[2624];
    int b2 = bid - 4096;
    if (b2 < 800) {
      int n = b2 / 32, dt = b2 % 32, d0 = dt * 64;
      const float* src = wl + ((size_t)n * 2048 + d0) * 41;
      for (int i = 0; i < 11; i++) { int lin = t + TB * i; if (lin < 2624) ld_f[lin] = src[lin]; }
      __syncthreads();
      unsigned short* dst = wlt + (size_t)n * 48 * 2048 + d0;
      for (int i = 0; i < 12; i++) {
        int lin = t + TB * i;  // 3072 = 48*64
        int wc = lin >> 6, d = lin & 63;
        float v = (wc < 41) ? ld_f[d * 41 + wc] : 0.f;
        dst[(size_t)wc * 2048 + d] = f2bf(v);
      }
    } else {
      int dt = b2 - 800, d0 = dt * 64;
      const float* src = wr + (size_t)d0 * 26;
      for (int i = 0; i < 7; i++) { int lin = t + TB * i; if (lin < 1664) ld_f[lin] = src[lin]; }
      __syncthreads();
      unsigned short* dst = wlt + (size_t)1200 * 2048 + d0;
      for (int i = 0; i < 8; i++) {
        int lin = t + TB * i;  // 2048 = 32*64
        int wc = lin >> 6, d = lin & 63;
        float v = (wc < 26) ? ld_f[d * 26 + wc] : 0.f;
        dst[(size_t)wc * 2048 + d] = f2bf(v);
      }
    }
  } else if (bid == 4928) {
    uint4* p = reinterpret_cast<uint4*>(wlt + (size_t)1232 * 2048);
    uint4 z = make_uint4(0, 0, 0, 0);
    for (int i = t; i < 12288; i += TB) p[i] = z;  // 48 cols x 2048
  } else {
    __shared__ int orred;
    if (t == 0) { orred = 0; pengl[0] = 0.f; }
    __syncthreads();
    int acc = 0;
    for (int i = t; i < 2048; i += TB) acc |= labraw[2 * i + 1];
    atomicOr(&orred, acc);
    __syncthreads();
    bool i64 = (orred == 0);
    for (int i = t; i < 4096; i += TB) lab32[i] = i64 ? labraw[2 * i] : labraw[i];
  }
}

// ---------------- kernel: unified GEMM (lvl2 + root cols), split-K=2 ----------------
// 640 blocks x 256 thr; tile 128x128, K-half 1024 (16 steps of 64); 4 waves 2x2 (64x64);
// single-buffer 32KB LDS, 2-barrier m97 loop; ~2.5 blocks/CU co-resident.
__global__ __launch_bounds__(TB) void k_gemm(const unsigned short* __restrict__ xbf,
                                             const unsigned short* __restrict__ wlt,
                                             float* __restrict__ part) {
  __shared__ __align__(16) unsigned char lds[32768];  // x 16K @0, w 16K @16384
  int bid = blockIdx.x;
  int ord = (bid & 7) * 80 + (bid >> 3);   // XCD-chunked, bijective (640 = 8*80)
  int rt = ord / 20, rem = ord % 20;       // each XCD: 4 rt x all (ct,kh) -> x slice L2-hot
  int ct = rem >> 1, kh = rem & 1;
  int r0 = rt * 128, c0 = ct * 128, k0 = kh * 1024;
  int tid = threadIdx.x, lane = tid & 63, wave = tid >> 6;
  int wavebase = wave * 64;
  int wr = wave >> 1, wc = wave & 1;
  int lq = lane >> 4, lr = lane & 15;
  f32x4 acc[4][4] = {};

#define STAGE_G(kk)                                                                   \
  do {                                                                                \
    _Pragma("unroll")                                                                 \
    for (int i = 0; i < 4; i++) { /* x: 1024 chunks, 128 rows */                      \
      int idx = i * 256 + tid;                                                        \
      int row = idx >> 3, s = idx & 7;                                                \
      const unsigned short* gp = xbf + (size_t)(r0 + row) * 2048 + (kk) + ((s ^ (row & 7)) << 3); \
      GLOAD16(gp, lds + (size_t)(i * 256 + wavebase) * 16);                           \
    }                                                                                 \
    _Pragma("unroll")                                                                 \
    for (int i = 0; i < 4; i++) { /* w: 1024 chunks, 128 cols */                      \
      int idx = i * 256 + tid;                                                        \
      int cl = idx >> 3, s = idx & 7;                                                 \
      const unsigned short* gp = wlt + (size_t)(c0 + cl) * 2048 + (kk) + ((s ^ (cl & 7)) << 3); \
      GLOAD16(gp, lds + 16384 + (size_t)(i * 256 + wavebase) * 16);                   \
    }                                                                                 \
  } while (0)

  for (int t = 0; t < 16; ++t) {
    STAGE_G(k0 + t * 64);
    __syncthreads();
#pragma unroll
    for (int ks = 0; ks < 2; ks++) {
      int g = (ks << 2) | lq;
      bf16x8 af[4], bx[4];
#pragma unroll
      for (int mt = 0; mt < 4; mt++) {
        int c = wc * 64 + mt * 16 + lr;
        af[mt] = *reinterpret_cast<const bf16x8*>(lds + 16384 + c * 128 + ((g ^ (c & 7)) << 4));
      }
#pragma unroll
      for (int nt = 0; nt < 4; nt++) {
        int r = wr * 64 + nt * 16 + lr;
        bx[nt] = *reinterpret_cast<const bf16x8*>(lds + r * 128 + ((g ^ (r & 7)) << 4));
      }
#pragma unroll
      for (int mt = 0; mt < 4; mt++)
#pragma unroll
        for (int nt = 0; nt < 4; nt++)
          acc[mt][nt] = __builtin_amdgcn_mfma_f32_16x16x32_bf16(af[mt], bx[nt], acc[mt][nt], 0, 0, 0);
    }
    __syncthreads();
  }

  float* pb = part + ((size_t)kh * 4096 + r0) * 1280 + c0;
#pragma unroll
  for (int nt = 0; nt < 4; nt++) {
    int row = wr * 64 + nt * 16 + lr;
#pragma unroll
    for (int mt = 0; mt < 4; mt++) {
      int col = wc * 64 + mt * 16 + lq * 4;
      *reinterpret_cast<f32x4*>(pb + (size_t)row * 1280 + col) = acc[mt][nt];
    }
  }
}

// ---------------- kernel: epilogue (partial-sum + root softmax + lvl2 softmax + out + penalty) ----
// 256 blocks x 512 thr; 16 rows/block; partials staged+summed in LDS (80 KB)
__global__ __launch_bounds__(512) void k_epi(const float* __restrict__ part,
                                             const float* __restrict__ br,
                                             const float* __restrict__ bl,
                                             const int* __restrict__ labels,
                                             float* __restrict__ out,
                                             float* __restrict__ pengl) {
  __shared__ float sum_[16 * 1280];   // 80 KB
  __shared__ float rpl[16 * 32];
  __shared__ float red[8];
  int bid = blockIdx.x, t = threadIdx.x;
  int r0 = bid * 16;
  // load + add the two K-partials, coalesced float4
  const float4* p0 = reinterpret_cast<const float4*>(part + (size_t)r0 * 1280);
  const float4* p1 = reinterpret_cast<const float4*>(part + (size_t)(4096 + r0) * 1280);
  float4* sm4 = reinterpret_cast<float4*>(sum_);
#pragma unroll
  for (int i = 0; i < 10; i++) {
    int idx = i * 512 + t;  // 5120 float4 = 16 rows * 320
    float4 a = p0[idx], b = p1[idx];
    sm4[idx] = make_float4(a.x + b.x, a.y + b.y, a.z + b.z, a.w + b.w);
  }
  __syncthreads();

  float pen = 0.f;
  // root softmax: threads 0..15, one row each (cols 1200..1225 + br)
  if (t < 16) {
    int row = t, b = r0 + row;
    float lg[26];
    float m = -1e30f;
#pragma unroll
    for (int c = 0; c < 26; c++) { lg[c] = sum_[row * 1280 + 1200 + c] + br[c]; m = fmaxf(m, lg[c]); }
    float s = 0.f;
#pragma unroll
    for (int c = 0; c < 26; c++) s += expf(lg[c] - m);
    float ls = logf(s);
#pragma unroll
    for (int c = 0; c < 26; c++) rpl[row * 32 + c] = expf(lg[c] - m - ls);
    int lab = labels[b];
    int j = lab / 40;
#pragma unroll
    for (int c = 0; c < 26; c++) if (c == j + 1) pen += 2.f * (m + ls - lg[c]);  // ce_root, x2 (scale /8192)
  }
  __syncthreads();

  // lvl2 softmax: thread (row = t>>5, n = t&31), n < 25
  int row = t >> 5, n = t & 31;
  if (n < 25) {
    int b = r0 + row;
    const float* sb = &sum_[row * 1280 + n * 48];
    float lg[41];
    float m = -1e30f;
#pragma unroll
    for (int c = 0; c < 41; c++) { lg[c] = sb[c] + bl[n * 41 + c]; m = fmaxf(m, lg[c]); }
    float s = 0.f;
#pragma unroll
    for (int c = 0; c < 41; c++) s += expf(lg[c] - m);
    float ls = logf(s);
    float rp = rpl[row * 32 + n + 1];
    int lab = labels[b];
    int j = lab / 40;
    int sub = (j == n) ? (lab - j * 40 + 1) : 0;
#pragma unroll
    for (int c = 0; c < 41; c++) if (c == sub) pen += (m + ls - lg[c]);
    float* ob = out + (size_t)b * 1000 + n * 40;
#pragma unroll
    for (int jj = 0; jj < 10; jj++) {
      float4 o;
      o.x = expf(lg[4 * jj + 1] - m - ls) * rp;
      o.y = expf(lg[4 * jj + 2] - m - ls) * rp;
      o.z = expf(lg[4 * jj + 3] - m - ls) * rp;
      o.w = expf(lg[4 * jj + 4] - m - ls) * rp;
      *reinterpret_cast<float4*>(ob + 4 * jj) = o;
    }
  }
  for (int off = 32; off; off >>= 1) pen += __shfl_down(pen, off);
  int lane = t & 63, wave = t >> 6;
  if (lane == 0) red[wave] = pen;
  __syncthreads();
  if (t == 0) {
    float tot = 0.f;
#pragma unroll
    for (int w = 0; w < 8; w++) tot += red[w];
    atomicAdd(pengl, tot * (1.f / 8192.f));
  }
}

extern "C" void kernel_launch(void* const* d_in, const int* in_sizes, int n_in,
                              void* d_out, int out_size, void* d_ws, size_t ws_size,
                              hipStream_t stream) {
  const float* x = (const float*)d_in[0];
  const int* labels_raw = (const int*)d_in[1];
  const float* wroot = (const float*)d_in[2];
  const float* broot = (const float*)d_in[3];
  const float* wlvl2 = (const float*)d_in[4];
  const float* blvl2 = (const float*)d_in[5];
  float* out = (float*)d_out;
  float* pengl = out + 4096000;

  char* ws = (char*)d_ws;
  unsigned short* xbf = (unsigned short*)ws;                    // 16,777,216 B
  unsigned short* wlt = (unsigned short*)(ws + 16777216);       //  5,242,880 B (1280 cols x 2048)
  float* part = (float*)(ws + 22020096);                        // 41,943,040 B (2 x 4096 x 1280 f32)
  int* lab32 = (int*)(ws + 63963136);                           //     16,384 B

  k_prep<<<4930, TB, 0, stream>>>(x, wlvl2, wroot, labels_raw, xbf, wlt, lab32, pengl);
  k_gemm<<<640, TB, 0, stream>>>(xbf, wlt, part);
  k_epi<<<256, 512, 0, stream>>>(part, broot, blvl2, lab32, out, pengl);
}